// Round 5
// baseline (337.395 us; speedup 1.0000x reference)
//
#include <hip/hip_runtime.h>
#include <hip/hip_cooperative_groups.h>
#include <math.h>

namespace cg = cooperative_groups;

// Problem constants
#define B_  4
#define S_  1024
#define D_  1024
#define H_  16

typedef __bf16 bf16x8 __attribute__((ext_vector_type(8)));
typedef float  f32x4  __attribute__((ext_vector_type(4)));

// ---- bf16 helpers (RNE) ----------------------------------------------------
__device__ __forceinline__ unsigned short f2bf(float f) {
  unsigned u = __builtin_bit_cast(unsigned, f);
  u = (u + 0x7FFFu + ((u >> 16) & 1u)) >> 16;
  return (unsigned short)u;
}
__device__ __forceinline__ float bf2f(unsigned short h) {
  unsigned u = ((unsigned)h) << 16;
  return __builtin_bit_cast(float, u);
}

// async global->LDS, 16 B per lane; LDS dest = wave-uniform base + lane*16
__device__ __forceinline__ void gl_lds16(const void* g, void* lds) {
  __builtin_amdgcn_global_load_lds(
      (const __attribute__((address_space(1))) unsigned int*)(unsigned long long)g,
      (__attribute__((address_space(3))) unsigned int*)(unsigned int)(unsigned long long)lds,
      16, 0, 0);
}

#define GM 64
#define GN 128

// ---------------------------------------------------------------------------
// Shared-memory overlay. Phases are separated by grid.sync(), so the three
// structs may alias. GEMM struct (largest): 3-buffer staging = 75.3 KB ->
// 2 blocks/CU (150.6 KB of 160).
// ---------------------------------------------------------------------------
struct SMemG {                                // GEMM phases (B, C)
  unsigned short As[3][2][GM * 32];           // 24 KB
  unsigned short Bs[3][2][GN * 32];           // 48 KB
  float gs[4][32];                            // q0-extra staging
  float q0s[128];
  float sc[64][9];                            // score cross-wave combine
};
struct SMemP {                                // prep phase (A)
  float tle[32][33];
  float gs2[4][32];
  float bgs[32];
};
struct SMemC {                                // conv phase (D)
  float msh[16], ish[16];
  float wT[48][68];
  float cbs[64];
  float pm[16][196];
};
union SMem {
  SMemG g;
  SMemP p;
  SMemC c;
};

// ---------------------------------------------------------------------------
// Shared MFMA K-loop: K=1024 in 16 tiles of 64, triple-buffered LDS,
// depth-2 prefetch, counted vmcnt (steady state 12 = 2 tiles in flight).
// Buf-reuse hazard (STAGE(t+2) -> buf[(t-1)%3]) is protected by iter t-1's
// trailing barrier (all ds_reads consumed by MFMAs before any wave passes).
// ---------------------------------------------------------------------------
__device__ __forceinline__ void kloop_mfma(
    const unsigned short* __restrict__ A, const unsigned short* __restrict__ BT,
    size_t aOff, size_t bOff0, size_t bOff1, int wv, int l15, int quad,
    SMemG& g, f32x4 (&acc)[4][2]) {
  auto STG = [&](int bufi, int kk) {
#pragma unroll
    for (int ks = 0; ks < 2; ++ks) {
      gl_lds16(A  + aOff  + kk + ks * 32, &g.As[bufi][ks][wv * 512]);
      gl_lds16(BT + bOff0 + kk + ks * 32, &g.Bs[bufi][ks][wv * 1024]);
      gl_lds16(BT + bOff1 + kk + ks * 32, &g.Bs[bufi][ks][wv * 1024 + 512]);
    }
  };
  STG(0, 0);
  STG(1, 64);
#pragma unroll 1
  for (int t = 0; t < 16; ++t) {
    const int cur = t - (t / 3) * 3;  // t % 3
    if (t < 14) {
      const int nb = (t + 2) - ((t + 2) / 3) * 3;
      STG(nb, (t + 2) * 64);
      asm volatile("s_waitcnt vmcnt(12)" ::: "memory");  // tile t retired
    } else if (t == 14) {
      asm volatile("s_waitcnt vmcnt(6)" ::: "memory");
    } else {
      asm volatile("s_waitcnt vmcnt(0)" ::: "memory");
    }
    __builtin_amdgcn_s_barrier();        // raw: in-flight loads cross it
    __builtin_amdgcn_sched_barrier(0);   // pin ds_reads below the barrier

#pragma unroll
    for (int ks = 0; ks < 2; ++ks) {
      bf16x8 af[4], bfr[2];
#pragma unroll
      for (int mi = 0; mi < 4; ++mi)
        af[mi] = *(const bf16x8*)(&g.As[cur][ks][(mi * 16 + l15) * 32 + quad * 8]);
#pragma unroll
      for (int ni = 0; ni < 2; ++ni)
        bfr[ni] = *(const bf16x8*)(
            &g.Bs[cur][ks][(wv * 32 + ni * 16 + l15) * 32 + quad * 8]);
#pragma unroll
      for (int mi = 0; mi < 4; ++mi)
#pragma unroll
        for (int ni = 0; ni < 2; ++ni)
          acc[mi][ni] = __builtin_amdgcn_mfma_f32_16x16x32_bf16(
              af[mi], bfr[ni], acc[mi][ni], 0, 0, 0);
    }
    __builtin_amdgcn_sched_barrier(0);   // keep next STAGE below the MFMAs
    __builtin_amdgcn_s_barrier();        // buf[cur] fully consumed
  }
}

// ---------------------------------------------------------------------------
// ROUND-17: single cooperative kernel, 512 blocks x 256 threads, 2 blocks/CU.
// Phase A: prep (W_G cast, Wk transpose, g0/biasK partials)
// Phase B: fusion GEMM WfT = WkT@W_G (blocks 0..127) || q0 partials (128..255)
//          || biasK (256..259) || rope table (260..387) || X cast (128..511)
// Phase C: K GEMM (Xbf@Wf+biasK) with fused RoPE+score+softmax-partials
// Phase D: softmax combine + conv1d + bias + ReLU
// ---------------------------------------------------------------------------
__global__ __launch_bounds__(256, 2) void fused_pipeline(
    const float* __restrict__ X, const int* __restrict__ mask,
    const float* __restrict__ W_G, const float* __restrict__ bG,
    const float* __restrict__ Wq, const float* __restrict__ bq,
    const float* __restrict__ Wk, const float* __restrict__ bk,
    const float* __restrict__ cw, const float* __restrict__ cb,
    float* __restrict__ out,
    unsigned short* __restrict__ Xbf, unsigned short* __restrict__ WGbf,
    unsigned short* __restrict__ WkT, unsigned short* __restrict__ WfT,
    float* __restrict__ part, float* __restrict__ partG,
    float* __restrict__ partB, float* __restrict__ biasK,
    float* __restrict__ tab, float* __restrict__ scores,
    float* __restrict__ mS) {
  __shared__ __align__(16) SMem sm;
  cg::grid_group grid = cg::this_grid();
  const int blk = blockIdx.x;
  const int tid = threadIdx.x;

  // ======================= PHASE A: prep =======================
  {
    // A1: W_G fp32 -> bf16 (all 512 blocks, 2048 elems each)
    const int i = (blk * 256 + tid) * 2;
    const float4 v0 = ((const float4*)W_G)[i];
    const float4 v1 = ((const float4*)W_G)[i + 1];
    ushort4 h0, h1;
    h0.x = f2bf(v0.x); h0.y = f2bf(v0.y); h0.z = f2bf(v0.z); h0.w = f2bf(v0.w);
    h1.x = f2bf(v1.x); h1.y = f2bf(v1.y); h1.z = f2bf(v1.z); h1.w = f2bf(v1.w);
    ((ushort4*)WGbf)[i] = h0;
    ((ushort4*)WGbf)[i + 1] = h1;

    // A2: Wk transpose+cast, 2 tiles of 32x32 per block
#pragma unroll 1
    for (int rep = 0; rep < 2; ++rep) {
      const int t = blk * 2 + rep;
      const int k0 = (t & 31) * 32;
      const int n0 = (t >> 5) * 32;
      const int tx = tid & 31;
      const int ty = tid >> 5;  // 0..7
      __syncthreads();  // tle reuse across reps
#pragma unroll
      for (int r = 0; r < 32; r += 8)
        sm.p.tle[ty + r][tx] = Wk[(size_t)(k0 + ty + r) * 1024 + n0 + tx];
      __syncthreads();
#pragma unroll
      for (int r = 0; r < 32; r += 8)
        WkT[(size_t)(n0 + ty + r) * 1024 + k0 + tx] = f2bf(sm.p.tle[tx][ty + r]);
    }

    // A3: g0 partials (blocks 0..127) / biasK partials (blocks 128..255)
    if (blk < 128) {
      const int sg = blk >> 2;          // k-slab 0..31
      const int mg = blk & 3;           // mid group 0..3
      __syncthreads();
      if (tid < 128) {
        const int b = tid >> 5, kk = tid & 31;
        sm.p.gs2[b][kk] = X[(size_t)b * S_ * D_ + sg * 32 + kk];
      }
      __syncthreads();
      const int mid = mg * 256 + tid;
      float a0 = 0.f, a1 = 0.f, a2 = 0.f, a3 = 0.f;
#pragma unroll
      for (int kk = 0; kk < 32; ++kk) {
        const float w = W_G[(size_t)(sg * 32 + kk) * 1024 + mid];
        a0 = fmaf(sm.p.gs2[0][kk], w, a0);
        a1 = fmaf(sm.p.gs2[1][kk], w, a1);
        a2 = fmaf(sm.p.gs2[2][kk], w, a2);
        a3 = fmaf(sm.p.gs2[3][kk], w, a3);
      }
      partG[(size_t)(sg * 4 + 0) * 1024 + mid] = a0;
      partG[(size_t)(sg * 4 + 1) * 1024 + mid] = a1;
      partG[(size_t)(sg * 4 + 2) * 1024 + mid] = a2;
      partG[(size_t)(sg * 4 + 3) * 1024 + mid] = a3;
    } else if (blk < 256) {
      const int bl = blk - 128;
      const int sl = bl >> 2;           // mid-slab 0..31
      const int ng = bl & 3;
      __syncthreads();
      if (tid < 32) sm.p.bgs[tid] = bG[sl * 32 + tid];
      __syncthreads();
      const int n = ng * 256 + tid;
      float a = 0.f;
#pragma unroll
      for (int kk = 0; kk < 32; ++kk)
        a = fmaf(sm.p.bgs[kk], Wk[(size_t)(sl * 32 + kk) * 1024 + n], a);
      partB[(size_t)sl * 1024 + n] = a;
    }
  }
  grid.sync();

  // ======================= PHASE B: fusion GEMM + extras =======================
  if (blk < 128) {
    // WfT = WkT @ W_G : bx = blk>>4 (N tiles 8), by = blk&15 (M tiles 16)
    const int wv   = tid >> 6;
    const int lane = tid & 63;
    const int l15  = lane & 15;
    const int quad = lane >> 4;
    const int m0 = (blk & 15) * GM;
    const int n0 = (blk >> 4) * GN;
    const int colOff = (lane & 3) * 8;
    const size_t aOff  = (size_t)(m0 + 16 * wv + (lane >> 2)) * 1024 + colOff;
    const size_t bOff0 = (size_t)(n0 + 32 * wv + (lane >> 2)) * 1024 + colOff;
    const size_t bOff1 = bOff0 + (size_t)16 * 1024;

    f32x4 acc[4][2];
#pragma unroll
    for (int i = 0; i < 4; ++i)
#pragma unroll
      for (int j = 0; j < 2; ++j) acc[i][j] = (f32x4){0.f, 0.f, 0.f, 0.f};

    kloop_mfma(WkT, WGbf, aOff, bOff0, bOff1, wv, l15, quad, sm.g, acc);

    // epilogue: C/D layout col = lane&15, row = quad*4 + r
#pragma unroll
    for (int ni = 0; ni < 2; ++ni) {
      const int n = n0 + wv * 32 + ni * 16 + l15;
#pragma unroll
      for (int mi = 0; mi < 4; ++mi) {
#pragma unroll
        for (int r = 0; r < 4; ++r) {
          const int m = m0 + mi * 16 + quad * 4 + r;
          WfT[(size_t)m * 1024 + n] = f2bf(acc[mi][ni][r]);
        }
      }
    }
  } else {
    if (blk < 256) {
      // q0 partial: part[(slab*4+b)*D+n] = sum_k g0[b,k]*Wq[k,n]
      const int eb = blk - 128;
      const int slab = eb >> 2;            // 0..31
      const int n = (eb & 3) * 256 + tid;  // 0..1023
      if (tid < 128) {
        const int b = tid >> 5, kk = tid & 31;
        float v = bG[slab * 32 + kk];
        const float* pg = partG + (size_t)b * 1024 + slab * 32 + kk;
#pragma unroll
        for (int sg = 0; sg < 32; ++sg) v += pg[(size_t)sg * 4096];
        sm.g.gs[b][kk] = v;
      }
      __syncthreads();
      float a0 = 0.f, a1 = 0.f, a2 = 0.f, a3 = 0.f;
#pragma unroll
      for (int kk = 0; kk < 32; ++kk) {
        const float w = Wq[(size_t)(slab * 32 + kk) * D_ + n];
        a0 = fmaf(sm.g.gs[0][kk], w, a0);
        a1 = fmaf(sm.g.gs[1][kk], w, a1);
        a2 = fmaf(sm.g.gs[2][kk], w, a2);
        a3 = fmaf(sm.g.gs[3][kk], w, a3);
      }
      part[(size_t)(slab * 4 + 0) * D_ + n] = a0;
      part[(size_t)(slab * 4 + 1) * D_ + n] = a1;
      part[(size_t)(slab * 4 + 2) * D_ + n] = a2;
      part[(size_t)(slab * 4 + 3) * D_ + n] = a3;
    } else if (blk < 260) {
      // biasK combine
      const int n = (blk - 256) * 256 + tid;
      float v = bk[n];
#pragma unroll
      for (int sl = 0; sl < 32; ++sl) v += partB[(size_t)sl * 1024 + n];
      biasK[n] = v;
    } else if (blk < 388) {
      // RoPE table
      const int idx = (blk - 260) * 256 + tid;
      const int s = idx >> 5, j = idx & 31;
      const float inv = (float)exp(-(double)j * (9.210340371976182736 / 32.0));
      float sn, c;
      sincosf((float)s * inv, &sn, &c);
      tab[(size_t)s * 64 + 2 * j] = c;
      tab[(size_t)s * 64 + 2 * j + 1] = sn;
    }
    // X fp32 -> bf16 cast: 2048 units over blocks 128..511
    for (int u = blk - 128; u < 2048; u += 384) {
      const int i = (u * 256 + tid) * 2;
      const float4 v0 = ((const float4*)X)[i];
      const float4 v1 = ((const float4*)X)[i + 1];
      ushort4 h0, h1;
      h0.x = f2bf(v0.x); h0.y = f2bf(v0.y); h0.z = f2bf(v0.z); h0.w = f2bf(v0.w);
      h1.x = f2bf(v1.x); h1.y = f2bf(v1.y); h1.z = f2bf(v1.z); h1.w = f2bf(v1.w);
      ((ushort4*)Xbf)[i] = h0;
      ((ushort4*)Xbf)[i + 1] = h1;
    }
  }
  grid.sync();

  // ======================= PHASE C: K GEMM + fused scores =======================
  {
    const int wv   = tid >> 6;
    const int lane = tid & 63;
    const int l15  = lane & 15;
    const int quad = lane >> 4;
    const int bx = blk >> 6;     // N tiles: 8 (head pairs)
    const int by = blk & 63;     // M tiles: 64
    const int m0 = by * GM;
    const int n0 = bx * GN;
    const int b_i   = m0 >> 10;
    const int sbase = m0 & 1023;

    // stage q0 (both heads of this block) into LDS
    if (tid < 128) {
      const int nq = n0 + tid;
      float v = bq[nq];
#pragma unroll
      for (int sl2 = 0; sl2 < 32; ++sl2)
        v += part[(size_t)(sl2 * 4 + b_i) * D_ + nq];
      sm.g.q0s[tid] = v;
    }
    __syncthreads();  // q0s visible to all waves; vmcnt clean before kloop

    const int colOff = (lane & 3) * 8;
    const size_t aOff  = (size_t)(m0 + 16 * wv + (lane >> 2)) * 1024 + colOff;
    const size_t bOff0 = (size_t)(n0 + 32 * wv + (lane >> 2)) * 1024 + colOff;
    const size_t bOff1 = bOff0 + (size_t)16 * 1024;

    f32x4 acc[4][2];
#pragma unroll
    for (int i = 0; i < 4; ++i)
#pragma unroll
      for (int j = 0; j < 2; ++j) acc[i][j] = (f32x4){0.f, 0.f, 0.f, 0.f};

    kloop_mfma(Xbf, WfT, aOff, bOff0, bOff1, wv, l15, quad, sm.g, acc);

    // fused RoPE + q0-dot + per-chunk softmax-partial epilogue
#pragma unroll
    for (int ni = 0; ni < 2; ++ni) {
      const int n_loc = wv * 32 + ni * 16 + l15;  // 0..127
      const float bv  = biasK[n0 + n_loc];
      const float q0a = sm.g.q0s[n_loc];
      const float q0b = sm.g.q0s[n_loc ^ 1];
      const float sq  = (n_loc & 1) ? -q0b : q0b;
      const int j2    = (n_loc & 63) & ~1;
#pragma unroll
      for (int mi = 0; mi < 4; ++mi) {
#pragma unroll
        for (int r = 0; r < 4; ++r) {
          const int s_loc = mi * 16 + quad * 4 + r;
          const float2 cs =
              *(const float2*)(tab + (size_t)(sbase + s_loc) * 64 + j2);
          const float coef = q0a * cs.x + sq * cs.y;
          float v = (acc[mi][ni][r] + bv) * coef;
          v += __shfl_xor(v, 1);
          v += __shfl_xor(v, 2);
          v += __shfl_xor(v, 4);
          v += __shfl_xor(v, 8);   // sum over 16 lanes (same quad = same s)
          if (l15 == 0) sm.g.sc[s_loc][wv * 2 + ni] = v;
        }
      }
    }
    __syncthreads();
    if (tid < 128) {
      const int h_loc = tid >> 6;   // wave0 = head0, wave1 = head1
      const int s_loc = tid & 63;
      const float* row = sm.g.sc[s_loc];
      float dot = (row[h_loc * 4 + 0] + row[h_loc * 4 + 1]) +
                  (row[h_loc * 4 + 2] + row[h_loc * 4 + 3]);
      dot *= 0.125f;  // 1/sqrt(64)
      const int s = sbase + s_loc;
      if (mask[b_i * S_ + s] == 0) dot = -1e9f;
      const int bh = b_i * H_ + (bx * 2 + h_loc);
      scores[(size_t)bh * S_ + s] = dot;
      float mx = dot;
#pragma unroll
      for (int off = 16; off >= 1; off >>= 1)
        mx = fmaxf(mx, __shfl_xor(mx, off, 32));
      float e = expf(dot - mx);
#pragma unroll
      for (int off = 16; off >= 1; off >>= 1) e += __shfl_xor(e, off, 32);
      if ((s_loc & 31) == 0) {
        const int ch = ((by & 15) << 1) + (s_loc >> 5);
        mS[((size_t)bh * 32 + ch) * 2 + 0] = mx;
        mS[((size_t)bh * 32 + ch) * 2 + 1] = e;
      }
    }
  }
  grid.sync();

  // ======================= PHASE D: conv + bias + ReLU =======================
  {
    const int sx = blk & 7;
    const int b  = (blk >> 3) & 3;
    const int oz = blk >> 5;
    const int s0 = sx * 128;
    const int o0 = oz * 64;
    const int tx = tid & 15;   // s group: 8 consecutive s at s0 + tx*8
    const int ty = tid >> 4;   // o group: 4 consecutive o at o0 + ty*4

    // softmax combine
    if (tid < 16) {
      const int bh = b * H_ + tid;
      float m = -3e38f;
#pragma unroll
      for (int c = 0; c < 32; ++c)
        m = fmaxf(m, mS[(size_t)(bh * 32 + c) * 2]);
      float S = 0.f;
#pragma unroll
      for (int c = 0; c < 32; ++c)
        S += mS[(size_t)(bh * 32 + c) * 2 + 1] *
             expf(mS[(size_t)(bh * 32 + c) * 2] - m);
      sm.c.msh[tid] = m;
      sm.c.ish[tid] = 1.f / S;
    }
    // weight tile, transposed: wT[ct][ol] = cw[(o0+ol)*48 + ct]
    for (int i = tid; i < 64 * 48; i += 256) {
      const int ol = i / 48, ct = i % 48;
      sm.c.wT[ct][ol] = cw[(size_t)(o0 + ol) * 48 + ct];
    }
    if (tid < 64) sm.c.cbs[tid] = cb[o0 + tid];
    __syncthreads();  // msh/ish ready

    // p halo, swizzled: col in [0,130) -> phys 12*(col>>3)+(col&7)
    for (int i = tid; i < 16 * 130; i += 256) {
      const int c = i / 130, col = i % 130;
      const int gs = s0 - 1 + col;
      sm.c.pm[c][12 * (col >> 3) + (col & 7)] =
          (gs >= 0 && gs < S_)
              ? expf(scores[(size_t)(b * H_ + c) * S_ + gs] - sm.c.msh[c]) *
                    sm.c.ish[c]
              : 0.f;
    }
    __syncthreads();

    float acc[4][8];
#pragma unroll
    for (int i = 0; i < 4; ++i) {
      const float cv = sm.c.cbs[ty * 4 + i];
#pragma unroll
      for (int j = 0; j < 8; ++j) acc[i][j] = cv;
    }

#pragma unroll
    for (int c = 0; c < 16; ++c) {
      float pl[10];
      const float* base = &sm.c.pm[c][12 * tx];
      *(float4*)(pl + 0) = *(const float4*)(base + 0);
      *(float4*)(pl + 4) = *(const float4*)(base + 4);
      *(float2*)(pl + 8) = *(const float2*)(&sm.c.pm[c][12 * (tx + 1)]);
#pragma unroll
      for (int t = 0; t < 3; ++t) {
        float w[4];
        *(float4*)w = *(const float4*)&sm.c.wT[c * 3 + t][ty * 4];
#pragma unroll
        for (int i = 0; i < 4; ++i)
#pragma unroll
          for (int j = 0; j < 8; ++j)
            acc[i][j] = fmaf(pl[j + t], w[i], acc[i][j]);
      }
    }

#pragma unroll
    for (int i = 0; i < 4; ++i) {
      float* orow =
          out + ((size_t)b * D_ + o0 + ty * 4 + i) * S_ + s0 + tx * 8;
      float4 v0, v1;
      v0.x = fmaxf(acc[i][0], 0.f); v0.y = fmaxf(acc[i][1], 0.f);
      v0.z = fmaxf(acc[i][2], 0.f); v0.w = fmaxf(acc[i][3], 0.f);
      v1.x = fmaxf(acc[i][4], 0.f); v1.y = fmaxf(acc[i][5], 0.f);
      v1.z = fmaxf(acc[i][6], 0.f); v1.w = fmaxf(acc[i][7], 0.f);
      *(float4*)(orow + 0) = v0;
      *(float4*)(orow + 4) = v1;
    }
  }
}

// ---------------------------------------------------------------------------
// Workspace layout (unchanged):
//  [ 0, 8M) Xbf | [16,18M) WkT | [18,20M) WGbf | [20,22M) WfT
//  [22M,+512K) part | +512K partG | [23M,+128K) partB | +128K biasK(4K)
//  +256K ropeT | +512K scores | +768K mS
// Single cooperative launch: 512 blocks x 256 threads, 2 blocks/CU.
// ---------------------------------------------------------------------------
extern "C" void kernel_launch(void* const* d_in, const int* in_sizes, int n_in,
                              void* d_out, int out_size, void* d_ws,
                              size_t ws_size, hipStream_t stream) {
  const float* x    = (const float*)d_in[0];
  const int*   mask = (const int*)d_in[1];
  const float* W_G  = (const float*)d_in[2];
  const float* b_G  = (const float*)d_in[3];
  const float* Wq   = (const float*)d_in[4];
  const float* bq   = (const float*)d_in[5];
  const float* Wk   = (const float*)d_in[6];
  const float* bk   = (const float*)d_in[7];
  const float* cw   = (const float*)d_in[8];
  const float* cb   = (const float*)d_in[9];
  float* out = (float*)d_out;

  char* ws = (char*)d_ws;
  unsigned short* Xbf  = (unsigned short*)(ws);
  unsigned short* WkT  = (unsigned short*)(ws + (16u << 20));
  unsigned short* WGbf = (unsigned short*)(ws + (18u << 20));
  unsigned short* WfT  = (unsigned short*)(ws + (20u << 20));
  float* part   = (float*)(ws + (22u << 20));
  float* partG  = (float*)(ws + (22u << 20) + (512u << 10));
  float* partB  = (float*)(ws + (23u << 20));
  float* biasK  = (float*)(ws + (23u << 20) + (128u << 10));
  float* ropeT  = (float*)(ws + (23u << 20) + (256u << 10));
  float* scores = (float*)(ws + (23u << 20) + (512u << 10));
  float* mS     = (float*)(ws + (23u << 20) + (768u << 10));

  void* args[] = {
      (void*)&x,    (void*)&mask, (void*)&W_G,  (void*)&b_G,  (void*)&Wq,
      (void*)&bq,   (void*)&Wk,   (void*)&bk,   (void*)&cw,   (void*)&cb,
      (void*)&out,  (void*)&Xbf,  (void*)&WGbf, (void*)&WkT,  (void*)&WfT,
      (void*)&part, (void*)&partG,(void*)&partB,(void*)&biasK,(void*)&ropeT,
      (void*)&scores,(void*)&mS};
  hipLaunchCooperativeKernel((void*)fused_pipeline, dim3(512), dim3(256),
                             args, 0, stream);
}

// Round 6
// 137.229 us; speedup vs baseline: 2.4586x; 2.4586x over previous
//
#include <hip/hip_runtime.h>
#include <math.h>

// Problem constants
#define B_  4
#define S_  1024
#define D_  1024
#define H_  16

typedef __bf16 bf16x8 __attribute__((ext_vector_type(8)));
typedef float  f32x4  __attribute__((ext_vector_type(4)));

// ---- bf16 helpers (RNE) ----------------------------------------------------
__device__ __forceinline__ unsigned short f2bf(float f) {
  unsigned u = __builtin_bit_cast(unsigned, f);
  u = (u + 0x7FFFu + ((u >> 16) & 1u)) >> 16;
  return (unsigned short)u;
}
__device__ __forceinline__ float bf2f(unsigned short h) {
  unsigned u = ((unsigned)h) << 16;
  return __builtin_bit_cast(float, u);
}

// async global->LDS, 16 B per lane; LDS dest = wave-uniform base + lane*16
__device__ __forceinline__ void gl_lds16(const void* g, void* lds) {
  __builtin_amdgcn_global_load_lds(
      (const __attribute__((address_space(1))) unsigned int*)(unsigned long long)g,
      (__attribute__((address_space(3))) unsigned int*)(unsigned int)(unsigned long long)lds,
      16, 0, 0);
}

// ---------------------------------------------------------------------------
// PREP (round-14 verbatim): only what the fusion GEMM launch reads.
//  blocks [   0, 512): W_G fp32 -> bf16 cast (row-major, BT operand of fusion)
//  blocks [ 512,1536): Wk transpose+cast -> WkT bf16 [n][mid]
//  blocks [1536,1664): g0 partials (fp32)
//  blocks [1664,1792): biasK partials
// ---------------------------------------------------------------------------
__global__ __launch_bounds__(256) void prep_kernel(
    const float* __restrict__ X, const float* __restrict__ W_G,
    const float* __restrict__ Wk, const float* __restrict__ bG,
    unsigned short* __restrict__ WGbf, unsigned short* __restrict__ WkT,
    float* __restrict__ partG, float* __restrict__ partB) {
  __shared__ float tle[32][33];
  __shared__ float gs2[4][32];
  __shared__ float bgs[32];
  const int blk = blockIdx.x;
  const int tid = threadIdx.x;

  if (blk < 512) {
    const int i = (blk * 256 + tid) * 2;
    const float4 v0 = ((const float4*)W_G)[i];
    const float4 v1 = ((const float4*)W_G)[i + 1];
    ushort4 h0, h1;
    h0.x = f2bf(v0.x); h0.y = f2bf(v0.y); h0.z = f2bf(v0.z); h0.w = f2bf(v0.w);
    h1.x = f2bf(v1.x); h1.y = f2bf(v1.y); h1.z = f2bf(v1.z); h1.w = f2bf(v1.w);
    ((ushort4*)WGbf)[i] = h0;
    ((ushort4*)WGbf)[i + 1] = h1;
  } else if (blk < 1536) {
    // Wk transpose+cast (32x32 tiles, LDS bounce)
    const int t = blk - 512;
    const int k0 = (t & 31) * 32;
    const int n0 = (t >> 5) * 32;
    const int tx = tid & 31;
    const int ty = tid >> 5;  // 0..7
#pragma unroll
    for (int r = 0; r < 32; r += 8)
      tle[ty + r][tx] = Wk[(size_t)(k0 + ty + r) * 1024 + n0 + tx];
    __syncthreads();
#pragma unroll
    for (int r = 0; r < 32; r += 8)
      WkT[(size_t)(n0 + ty + r) * 1024 + k0 + tx] = f2bf(tle[tx][ty + r]);
  } else if (blk < 1664) {
    // g0 partials: fp32, reads X row 0 of each batch + a W_G slab
    const int bl = blk - 1536;       // 0..127
    const int sg = bl >> 2;          // k-slab 0..31
    const int mg = bl & 3;           // mid group 0..3
    if (tid < 128) {
      const int b = tid >> 5, kk = tid & 31;
      gs2[b][kk] = X[(size_t)b * S_ * D_ + sg * 32 + kk];
    }
    __syncthreads();
    const int mid = mg * 256 + tid;
    float a0 = 0.f, a1 = 0.f, a2 = 0.f, a3 = 0.f;
#pragma unroll
    for (int kk = 0; kk < 32; ++kk) {
      const float w = W_G[(size_t)(sg * 32 + kk) * 1024 + mid];
      a0 = fmaf(gs2[0][kk], w, a0);
      a1 = fmaf(gs2[1][kk], w, a1);
      a2 = fmaf(gs2[2][kk], w, a2);
      a3 = fmaf(gs2[3][kk], w, a3);
    }
    partG[(size_t)(sg * 4 + 0) * 1024 + mid] = a0;
    partG[(size_t)(sg * 4 + 1) * 1024 + mid] = a1;
    partG[(size_t)(sg * 4 + 2) * 1024 + mid] = a2;
    partG[(size_t)(sg * 4 + 3) * 1024 + mid] = a3;
  } else {
    // biasK partials: partB[sl][n] = sum_{mid in slab} b_G[mid]*Wk[mid][n]
    const int bl = blk - 1664;       // 0..127
    const int sl = bl >> 2;          // mid-slab 0..31
    const int ng = bl & 3;
    if (tid < 32) bgs[tid] = bG[sl * 32 + tid];
    __syncthreads();
    const int n = ng * 256 + tid;
    float a = 0.f;
#pragma unroll
    for (int kk = 0; kk < 32; ++kk)
      a = fmaf(bgs[kk], Wk[(size_t)(sl * 32 + kk) * 1024 + n], a);
    partB[(size_t)sl * 1024 + n] = a;
  }
}

// ---------------------------------------------------------------------------
// bf16 MFMA GEMM — ROUND-18: depth-2 prefetch (triple-buffered LDS, counted
// vmcnt(12) steady state: two 64-K tiles in flight across the barriers).
// Proven correct inside R5's cooperative kernel; here in the R4 multi-launch
// structure. Raw s_barriers (no vmcnt(0) drain); buf-reuse hazard protected
// by the trailing barrier of the iteration using that buffer.
// ---------------------------------------------------------------------------
#define GM 64
#define GN 128

__global__ __launch_bounds__(256) void gemm_bf16(
    const unsigned short* __restrict__ A, const unsigned short* __restrict__ BT,
    const float* __restrict__ bias, unsigned short* __restrict__ C,
    const int mShift, const int nGemmBlocks,
    const float* __restrict__ Wq, float* __restrict__ part,
    const float* __restrict__ partG, const float* __restrict__ bG,
    const float* __restrict__ partB, const float* __restrict__ bk,
    float* __restrict__ biasK,
    const float* __restrict__ X, unsigned short* __restrict__ Xbf,
    float* __restrict__ tab,
    const float* __restrict__ bq, const int* __restrict__ mask,
    float* __restrict__ scores, float* __restrict__ mS) {
  __shared__ __align__(16) unsigned short As[3][2][GM * 32];   // 24 KB
  __shared__ __align__(16) unsigned short Bs[3][2][GN * 32];   // 48 KB
  __shared__ float gs[4][32];
  __shared__ float q0s[128];
  __shared__ float sc[64][9];   // [s_loc][wv*2+ni], +1 pad col

  const int flat = blockIdx.x;
  const int tid  = threadIdx.x;

  if (flat >= nGemmBlocks) {
    const int eb = flat - nGemmBlocks;
    if (eb < 128) {
      // ---- fused q0 partial: part[(slab*4+b)*D+n] = sum_k g0[b,k]*Wq[k,n]
      const int slab = eb >> 2;            // 0..31 (k-slab of q0 GEMV)
      const int n = (eb & 3) * 256 + tid;  // 0..1023
      if (tid < 128) {
        const int b = tid >> 5, kk = tid & 31;
        float v = bG[slab * 32 + kk];
        const float* pg = partG + (size_t)b * 1024 + slab * 32 + kk;
#pragma unroll
        for (int sg = 0; sg < 32; ++sg) v += pg[(size_t)sg * 4096];
        gs[b][kk] = v;
      }
      __syncthreads();
      float a0 = 0.f, a1 = 0.f, a2 = 0.f, a3 = 0.f;
#pragma unroll
      for (int kk = 0; kk < 32; ++kk) {
        const float w = Wq[(size_t)(slab * 32 + kk) * D_ + n];
        a0 = fmaf(gs[0][kk], w, a0);
        a1 = fmaf(gs[1][kk], w, a1);
        a2 = fmaf(gs[2][kk], w, a2);
        a3 = fmaf(gs[3][kk], w, a3);
      }
      part[(size_t)(slab * 4 + 0) * D_ + n] = a0;
      part[(size_t)(slab * 4 + 1) * D_ + n] = a1;
      part[(size_t)(slab * 4 + 2) * D_ + n] = a2;
      part[(size_t)(slab * 4 + 3) * D_ + n] = a3;
    } else if (eb < 132) {
      // ---- biasK combine: biasK[n] = bk[n] + sum_sl partB[sl][n]
      const int n = (eb - 128) * 256 + tid;
      float v = bk[n];
#pragma unroll
      for (int sl = 0; sl < 32; ++sl) v += partB[(size_t)sl * 1024 + n];
      biasK[n] = v;
    } else if (eb < 260) {
      // ---- RoPE table: tab[s*64+2j]=cos(s*inv_j), +1 = sin
      const int idx = (eb - 132) * 256 + tid;
      const int s = idx >> 5, j = idx & 31;
      const float inv = (float)exp(-(double)j * (9.210340371976182736 / 32.0));
      float sn, c;
      sincosf((float)s * inv, &sn, &c);
      tab[(size_t)s * 64 + 2 * j] = c;
      tab[(size_t)s * 64 + 2 * j + 1] = sn;
    } else {
      // ---- X fp32 -> bf16 cast (consumer is the NEXT launch)
      const int i = ((eb - 260) * 256 + tid) * 2;  // float4 index
      const float4 v0 = ((const float4*)X)[i];
      const float4 v1 = ((const float4*)X)[i + 1];
      ushort4 h0, h1;
      h0.x = f2bf(v0.x); h0.y = f2bf(v0.y); h0.z = f2bf(v0.z); h0.w = f2bf(v0.w);
      h1.x = f2bf(v1.x); h1.y = f2bf(v1.y); h1.z = f2bf(v1.z); h1.w = f2bf(v1.w);
      ((ushort4*)Xbf)[i] = h0;
      ((ushort4*)Xbf)[i + 1] = h1;
    }
    return;
  }

  // ---- GEMM path ----
  const int bx = flat >> mShift;               // N tiles: 8
  const int by = flat & ((1 << mShift) - 1);   // M tiles: 16 or 64
  const int wv   = tid >> 6;
  const int lane = tid & 63;
  const int m0 = by * GM;
  const int n0 = bx * GN;

  // score mode: stage q0 (both heads of this block) into LDS before the loop.
  // Its global loads retire before the kloop's first counted vmcnt matters
  // (vmcnt counts oldest-first; see loop comment). q0s is read only in the
  // epilogue, after multiple barriers.
  if (scores && tid < 128) {
    const int nq = n0 + tid;
    float v = bq[nq];
#pragma unroll
    for (int sl2 = 0; sl2 < 32; ++sl2)
      v += part[(size_t)(sl2 * 4 + (m0 >> 10)) * D_ + nq];
    q0s[tid] = v;
  }

  const int colOff = (lane & 3) * 8;
  const size_t aOff  = (size_t)(m0 + 16 * wv + (lane >> 2)) * 1024 + colOff;
  const size_t bOff0 = (size_t)(n0 + 32 * wv + (lane >> 2)) * 1024 + colOff;
  const size_t bOff1 = bOff0 + (size_t)16 * 1024;

  const int l15  = lane & 15;
  const int quad = lane >> 4;

  f32x4 acc[4][2];
#pragma unroll
  for (int i = 0; i < 4; ++i)
#pragma unroll
    for (int j = 0; j < 2; ++j) acc[i][j] = (f32x4){0.f, 0.f, 0.f, 0.f};

  // stage one 64-wide K-tile into LDS buffer bufi (6 loads/thread)
  auto STG = [&](int bufi, int kk) {
#pragma unroll
    for (int ks = 0; ks < 2; ++ks) {
      gl_lds16(A  + aOff  + kk + ks * 32, &As[bufi][ks][wv * 512]);
      gl_lds16(BT + bOff0 + kk + ks * 32, &Bs[bufi][ks][wv * 1024]);
      gl_lds16(BT + bOff1 + kk + ks * 32, &Bs[bufi][ks][wv * 1024 + 512]);
    }
  };

  STG(0, 0);
  STG(1, 64);

#pragma unroll 1
  for (int t = 0; t < 16; ++t) {
    const int cur = t - (t / 3) * 3;  // t % 3
    if (t < 14) {
      const int nb = (t + 2) - ((t + 2) / 3) * 3;
      STG(nb, (t + 2) * 64);
      // outstanding: tiles t, t+1, t+2 (18 loads) -> wait until 12 left:
      // tile t's 6 retired; 12 stay in flight across both barriers.
      asm volatile("s_waitcnt vmcnt(12)" ::: "memory");
    } else if (t == 14) {
      asm volatile("s_waitcnt vmcnt(6)" ::: "memory");
    } else {
      asm volatile("s_waitcnt vmcnt(0)" ::: "memory");
    }
    __builtin_amdgcn_s_barrier();        // raw: in-flight loads cross it
    __builtin_amdgcn_sched_barrier(0);   // pin ds_reads below the barrier

#pragma unroll
    for (int ks = 0; ks < 2; ++ks) {
      bf16x8 af[4], bfr[2];
#pragma unroll
      for (int mi = 0; mi < 4; ++mi)
        af[mi] = *(const bf16x8*)(&As[cur][ks][(mi * 16 + l15) * 32 + quad * 8]);
#pragma unroll
      for (int ni = 0; ni < 2; ++ni)
        bfr[ni] = *(const bf16x8*)(
            &Bs[cur][ks][(wv * 32 + ni * 16 + l15) * 32 + quad * 8]);
#pragma unroll
      for (int mi = 0; mi < 4; ++mi)
#pragma unroll
        for (int ni = 0; ni < 2; ++ni)
          acc[mi][ni] = __builtin_amdgcn_mfma_f32_16x16x32_bf16(
              af[mi], bfr[ni], acc[mi][ni], 0, 0, 0);
    }
    __builtin_amdgcn_sched_barrier(0);   // keep next STG below the MFMAs
    __builtin_amdgcn_s_barrier();        // buf[cur] fully consumed
  }

  if (scores) {
    // ---- fused RoPE + q0-dot + per-chunk softmax-partial epilogue ----
    const int b_i   = m0 >> 10;
    const int sbase = m0 & 1023;
#pragma unroll
    for (int ni = 0; ni < 2; ++ni) {
      const int n_loc = wv * 32 + ni * 16 + l15;  // 0..127
      const float bv  = bias[n0 + n_loc];
      const float q0a = q0s[n_loc];
      const float q0b = q0s[n_loc ^ 1];
      const float sq  = (n_loc & 1) ? -q0b : q0b;
      const int j2    = (n_loc & 63) & ~1;
#pragma unroll
      for (int mi = 0; mi < 4; ++mi) {
#pragma unroll
        for (int r = 0; r < 4; ++r) {
          const int s_loc = mi * 16 + quad * 4 + r;
          const float2 cs =
              *(const float2*)(tab + (size_t)(sbase + s_loc) * 64 + j2);
          const float coef = q0a * cs.x + sq * cs.y;
          float v = (acc[mi][ni][r] + bv) * coef;
          v += __shfl_xor(v, 1);
          v += __shfl_xor(v, 2);
          v += __shfl_xor(v, 4);
          v += __shfl_xor(v, 8);   // sum over 16 lanes (same quad = same s)
          if (l15 == 0) sc[s_loc][wv * 2 + ni] = v;
        }
      }
    }
    __syncthreads();
    if (tid < 128) {
      const int h_loc = tid >> 6;   // wave0 = head0, wave1 = head1
      const int s_loc = tid & 63;
      const float* row = sc[s_loc];
      float dot = (row[h_loc * 4 + 0] + row[h_loc * 4 + 1]) +
                  (row[h_loc * 4 + 2] + row[h_loc * 4 + 3]);
      dot *= 0.125f;  // 1/sqrt(64)
      const int s = sbase + s_loc;
      if (mask[b_i * S_ + s] == 0) dot = -1e9f;
      const int bh = b_i * H_ + (bx * 2 + h_loc);
      scores[(size_t)bh * S_ + s] = dot;
      float mx = dot;
#pragma unroll
      for (int off = 16; off >= 1; off >>= 1)
        mx = fmaxf(mx, __shfl_xor(mx, off, 32));
      float e = expf(dot - mx);
#pragma unroll
      for (int off = 16; off >= 1; off >>= 1) e += __shfl_xor(e, off, 32);
      if ((s_loc & 31) == 0) {
        const int ch = ((by & 15) << 1) + (s_loc >> 5);
        mS[((size_t)bh * 32 + ch) * 2 + 0] = mx;
        mS[((size_t)bh * 32 + ch) * 2 + 1] = e;
      }
    }
    return;
  }

  // epilogue: C/D layout col = lane&15, row = quad*4 + r (m89/m91 verified)
#pragma unroll
  for (int ni = 0; ni < 2; ++ni) {
    const int n = n0 + wv * 32 + ni * 16 + l15;
    const float bv = bias ? bias[n] : 0.f;
#pragma unroll
    for (int mi = 0; mi < 4; ++mi) {
#pragma unroll
      for (int r = 0; r < 4; ++r) {
        const int m = m0 + mi * 16 + quad * 4 + r;
        C[(size_t)m * 1024 + n] = f2bf(acc[mi][ni][r] + bv);
      }
    }
  }
}

// ---------------------------------------------------------------------------
// Conv1d (16->1024, k=3, pad=1) + bias + ReLU — ROUND-18 v5.
// v4 suspects: 2 blocks/CU + serial 16-thread softmax-combine prologue.
// v5: 64o x 64s tiles -> grid 16x4x16 = 1024 blocks (4/CU, 16 waves/CU);
// per-thread 2o x 8s; softmax combine parallelized over 128 threads
// (8 segments/head + __shfl_xor tree; max identical, sum reassociated).
// pm swizzle phys = 12*(col>>3)+(col&7), row stride 104 (16B-aligned rows).
// Summation order per output unchanged (c-major, t-minor, bias-first).
// ---------------------------------------------------------------------------
__global__ __launch_bounds__(256) void conv_norm_relu_kernel(
    const float* __restrict__ scores, const float* __restrict__ mS,
    const float* __restrict__ cw, const float* __restrict__ cb,
    float* __restrict__ out) {
  const int b  = blockIdx.y;
  const int s0 = blockIdx.x * 64;
  const int o0 = blockIdx.z * 64;
  const int tid = threadIdx.x;
  const int tx = tid & 7;    // s group: 8 consecutive s at s0 + tx*8
  const int ty = tid >> 3;   // o group: 2 consecutive o at o0 + ty*2

  __shared__ float msh[16], ish[16];
  __shared__ __align__(16) float wT[48][68];   // [ct][o-local], 12.75 KB
  __shared__ float cbs[64];
  __shared__ __align__(16) float pm[16][104];  // swizzled p halo, 6.5 KB

  // softmax combine, 128 threads: head h = tid>>3, segment seg = tid&7
  if (tid < 128) {
    const int h = tid >> 3, seg = tid & 7;
    const int bh = b * H_ + h;
    const float* base = mS + (size_t)bh * 64 + seg * 8;  // 4 chunks * 2
    float m = -3e38f;
#pragma unroll
    for (int q = 0; q < 4; ++q) m = fmaxf(m, base[q * 2]);
    m = fmaxf(m, __shfl_xor(m, 1));
    m = fmaxf(m, __shfl_xor(m, 2));
    m = fmaxf(m, __shfl_xor(m, 4));   // group of 8 lanes = one head
    float S = 0.f;
#pragma unroll
    for (int q = 0; q < 4; ++q) S += base[q * 2 + 1] * expf(base[q * 2] - m);
    S += __shfl_xor(S, 1);
    S += __shfl_xor(S, 2);
    S += __shfl_xor(S, 4);
    if (seg == 0) {
      msh[h] = m;
      ish[h] = 1.f / S;
    }
  }
  // weight tile, transposed: wT[ct][ol] = cw[(o0+ol)*48 + ct]
  for (int i = tid; i < 64 * 48; i += 256) {
    const int ol = i / 48, ct = i % 48;
    wT[ct][ol] = cw[(size_t)(o0 + ol) * 48 + ct];
  }
  if (tid < 64) cbs[tid] = cb[o0 + tid];
  __syncthreads();  // msh/ish ready

  // p halo, swizzled: logical col in [0,66) -> phys 12*(col>>3)+(col&7)
  for (int i = tid; i < 16 * 66; i += 256) {
    const int c = i / 66, col = i % 66;
    const int gs = s0 - 1 + col;
    pm[c][12 * (col >> 3) + (col & 7)] =
        (gs >= 0 && gs < S_)
            ? expf(scores[(size_t)(b * H_ + c) * S_ + gs] - msh[c]) * ish[c]
            : 0.f;
  }
  __syncthreads();

  float acc[2][8];
#pragma unroll
  for (int i = 0; i < 2; ++i) {
    const float cv = cbs[ty * 2 + i];
#pragma unroll
    for (int j = 0; j < 8; ++j) acc[i][j] = cv;
  }

#pragma unroll
  for (int c = 0; c < 16; ++c) {
    float pl[10];
    const float* base = &pm[c][12 * tx];
    *(float4*)(pl + 0) = *(const float4*)(base + 0);
    *(float4*)(pl + 4) = *(const float4*)(base + 4);
    *(float2*)(pl + 8) = *(const float2*)(&pm[c][12 * (tx + 1)]);
#pragma unroll
    for (int t = 0; t < 3; ++t) {
      float w[2];
      *(float2*)w = *(const float2*)&wT[c * 3 + t][ty * 2];
#pragma unroll
      for (int i = 0; i < 2; ++i)
#pragma unroll
        for (int j = 0; j < 8; ++j)
          acc[i][j] = fmaf(pl[j + t], w[i], acc[i][j]);
    }
  }

#pragma unroll
  for (int i = 0; i < 2; ++i) {
    float* orow =
        out + ((size_t)b * D_ + o0 + ty * 2 + i) * S_ + s0 + tx * 8;
    float4 v0, v1;
    v0.x = fmaxf(acc[i][0], 0.f); v0.y = fmaxf(acc[i][1], 0.f);
    v0.z = fmaxf(acc[i][2], 0.f); v0.w = fmaxf(acc[i][3], 0.f);
    v1.x = fmaxf(acc[i][4], 0.f); v1.y = fmaxf(acc[i][5], 0.f);
    v1.z = fmaxf(acc[i][6], 0.f); v1.w = fmaxf(acc[i][7], 0.f);
    *(float4*)(orow + 0) = v0;
    *(float4*)(orow + 4) = v1;
  }
}

// ---------------------------------------------------------------------------
// Workspace layout (round-14):
//  [ 0, 8M) Xbf | [16,18M) WkT | [18,20M) WGbf | [20,22M) WfT
//  [22M,+512K) part | +512K partG | [23M,+128K) partB | +128K biasK(4K)
//  +256K ropeT | +512K scores | +768K mS
// Pipeline (4 launches):
//  prep -> fusion GEMM(WfT = WkT@W_G) + q0/biasK/rope/Xcast extras
//       -> K GEMM with fused RoPE+score+softmax-partial epilogue -> conv.
// ---------------------------------------------------------------------------
extern "C" void kernel_launch(void* const* d_in, const int* in_sizes, int n_in,
                              void* d_out, int out_size, void* d_ws,
                              size_t ws_size, hipStream_t stream) {
  const float* x    = (const float*)d_in[0];
  const int*   mask = (const int*)d_in[1];
  const float* W_G  = (const float*)d_in[2];
  const float* b_G  = (const float*)d_in[3];
  const float* Wq   = (const float*)d_in[4];
  const float* bq   = (const float*)d_in[5];
  const float* Wk   = (const float*)d_in[6];
  const float* bk   = (const float*)d_in[7];
  const float* cw   = (const float*)d_in[8];
  const float* cb   = (const float*)d_in[9];
  float* out = (float*)d_out;

  char* ws = (char*)d_ws;
  unsigned short* Xbf  = (unsigned short*)(ws);
  unsigned short* WkT  = (unsigned short*)(ws + (16u << 20));
  unsigned short* WGbf = (unsigned short*)(ws + (18u << 20));
  unsigned short* WfT  = (unsigned short*)(ws + (20u << 20));
  float* part   = (float*)(ws + (22u << 20));
  float* partG  = (float*)(ws + (22u << 20) + (512u << 10));
  float* partB  = (float*)(ws + (23u << 20));
  float* biasK  = (float*)(ws + (23u << 20) + (128u << 10));
  float* ropeT  = (float*)(ws + (23u << 20) + (256u << 10));
  float* scores = (float*)(ws + (23u << 20) + (512u << 10));
  float* mS     = (float*)(ws + (23u << 20) + (768u << 10));

  // 1) W_G cast, WkT transpose, fp32 g0/biasK partials (fusion-launch inputs)
  prep_kernel<<<1792, 256, 0, stream>>>(x, W_G, Wk, b_G, WGbf, WkT,
                                        partG, partB);
  // 2) WfT = WkT @ W_G (128 GEMM blocks) + extras: q0 partials (128),
  //    biasK combine (4), RoPE table (128), X bf16 cast (2048)
  gemm_bf16<<<2436, 256, 0, stream>>>(WkT, WGbf, nullptr, WfT, 4, 128,
                                      Wq, part, partG, b_G, partB, bk, biasK,
                                      x, Xbf, ropeT,
                                      nullptr, nullptr, nullptr, nullptr);
  // 3) K = Xbf @ Wf + biasK, fused into scores + per-chunk softmax partials
  gemm_bf16<<<512, 256, 0, stream>>>(Xbf, WfT, biasK, nullptr, 6, 512,
                                     nullptr, part, nullptr, nullptr,
                                     nullptr, nullptr, nullptr,
                                     nullptr, nullptr, ropeT,
                                     bq, mask, scores, mS);
  // 4) softmax combine + conv1d + bias + ReLU (1024 blocks, 4/CU)
  conv_norm_relu_kernel<<<dim3(16, B_, 16), 256, 0, stream>>>(
      scores, mS, cw, cb, out);
}